// Round 1
// baseline (602.475 us; speedup 1.0000x reference)
//
#include <hip/hip_runtime.h>
#include <stdint.h>

#define BATCH 4
#define HEADS 12
#define SEQ   2048
#define DIM   64
#define BH    48
#define NELEM (BH*SEQ*DIM)          // 6291456
#define QBLK  16
#define NBLK  (BH*(SEQ/QBLK))       // 6144

typedef __attribute__((ext_vector_type(4))) float f32x4;
typedef __attribute__((ext_vector_type(8))) short bf16x8;

__device__ __forceinline__ unsigned short f2bf(float x){
  unsigned int u = __float_as_uint(x);
  u += 0x7fffu + ((u >> 16) & 1u);
  return (unsigned short)(u >> 16);
}
__device__ __forceinline__ float bf2f(unsigned int h){
  return __uint_as_float(h << 16);
}

// ---------------- prep: K -> (Khi, Klo) bf16 split ----------------
__global__ void prep_split_k(const float* __restrict__ K,
                             unsigned short* __restrict__ Khi,
                             unsigned short* __restrict__ Klo){
  const int n4 = NELEM/4;
  for (int i = blockIdx.x*blockDim.x + threadIdx.x; i < n4; i += gridDim.x*blockDim.x){
    float4 k = ((const float4*)K)[i];
    float kv[4] = {k.x,k.y,k.z,k.w};
    unsigned short h[4], lo[4];
    #pragma unroll
    for (int j=0;j<4;++j){
      h[j]  = f2bf(kv[j]);
      lo[j] = f2bf(kv[j] - bf2f(h[j]));
    }
    uint2 hp, lp;
    hp.x = (unsigned)h[0]  | ((unsigned)h[1]<<16);
    hp.y = (unsigned)h[2]  | ((unsigned)h[3]<<16);
    lp.x = (unsigned)lo[0] | ((unsigned)lo[1]<<16);
    lp.y = (unsigned)lo[2] | ((unsigned)lo[3]<<16);
    ((uint2*)Khi)[i] = hp;
    ((uint2*)Klo)[i] = lp;
  }
}

// ---------------- prep: V -> Vt bf16 transposed [bh][d][s] ----------------
__global__ void prep_transpose_v(const float* __restrict__ V,
                                 unsigned short* __restrict__ Vt){
  __shared__ float tile[64][65];
  int bh = blockIdx.x >> 5;          // 32 s-chunks of 64
  int s0 = (blockIdx.x & 31) << 6;
  int t  = threadIdx.x;              // 256 threads
  const float* Vb = V + ((size_t)bh*SEQ + s0)*DIM;
  #pragma unroll
  for (int r=0;r<4;++r){
    int f = r*1024 + t*4;
    int s = f >> 6, d = f & 63;
    float4 v = *(const float4*)(Vb + f);
    tile[s][d+0]=v.x; tile[s][d+1]=v.y; tile[s][d+2]=v.z; tile[s][d+3]=v.w;
  }
  __syncthreads();
  int d = t >> 2, si = (t & 3) << 4;
  unsigned int o[8];
  #pragma unroll
  for (int u=0;u<8;++u){
    unsigned short a = f2bf(tile[si+2*u  ][d]);
    unsigned short b = f2bf(tile[si+2*u+1][d]);
    o[u] = (unsigned)a | ((unsigned)b<<16);
  }
  unsigned short* orow = Vt + (size_t)bh*DIM*SEQ + (size_t)d*SEQ + s0 + si;
  uint4 p0 = make_uint4(o[0],o[1],o[2],o[3]);
  uint4 p1 = make_uint4(o[4],o[5],o[6],o[7]);
  ((uint4*)orow)[0] = p0;
  ((uint4*)orow)[1] = p1;
}

// ---------------- main fused attention ----------------
// P_lds byte address with XOR swizzle (row stride 4096B, 16B-slot swizzle)
#define PB(q,kv) ((((q)<<12) + ((kv)<<1)) ^ (((q)&7)<<4))

__global__ __launch_bounds__(512, 2) void attn_main(
    const float* __restrict__ Q,
    const unsigned short* __restrict__ Khi,
    const unsigned short* __restrict__ Klo,
    const unsigned short* __restrict__ Vt,
    float* __restrict__ ctx_out,
    float* __restrict__ attn_out){

  __shared__ unsigned short Psh[QBLK*SEQ];   // 64 KB, swizzled bf16 P
  __shared__ float red[8*QBLK];
  __shared__ float rinv_s[QBLK];
  __shared__ float ctile[4*QBLK*16];         // 4 KB cross-wave ctx reduce

  char* Pb = (char*)Psh;
  int tid = threadIdx.x;
  int w = tid >> 6, l = tid & 63;
  int lr = l & 15, lg = l >> 4;

  // XCD-aware bijective swizzle (6144 % 8 == 0)
  int bid = blockIdx.x;
  int swz = (bid & 7)*(NBLK/8) + (bid >> 3);
  int bh = swz >> 7;                 // head index (48)
  int q0 = (swz & 127) << 4;         // q-tile base

  // ---- Q fragments: scale 1/8, hi/lo bf16 split, direct from global ----
  const float* Qrow = Q + ((size_t)(bh*SEQ) + q0 + lr)*DIM + lg*8;
  bf16x8 qh[2], ql[2];
  #pragma unroll
  for (int ks=0; ks<2; ++ks){
    float4 a = *(const float4*)(Qrow + ks*32);
    float4 b = *(const float4*)(Qrow + ks*32 + 4);
    float x[8] = {a.x,a.y,a.z,a.w,b.x,b.y,b.z,b.w};
    #pragma unroll
    for (int j=0;j<8;++j){
      float v = x[j]*0.125f;
      unsigned short h = f2bf(v);
      qh[ks][j] = (short)h;
      ql[ks][j] = (short)f2bf(v - bf2f(h));
    }
  }

  const unsigned short* Khb = Khi + (size_t)bh*SEQ*DIM;
  const unsigned short* Klb = Klo + (size_t)bh*SEQ*DIM;

  // ---- phase 1: QK^T (split 3-term MFMA), exp, P->LDS, partial rowsums ----
  float rs[4] = {0.f,0.f,0.f,0.f};
  for (int t=0; t<16; ++t){
    int kv0 = w*256 + t*16;
    const unsigned short* kr_h = Khb + (size_t)(kv0 + lr)*DIM + lg*8;
    const unsigned short* kr_l = Klb + (size_t)(kv0 + lr)*DIM + lg*8;
    bf16x8 kh0 = *(const bf16x8*)(kr_h);
    bf16x8 kh1 = *(const bf16x8*)(kr_h + 32);
    bf16x8 kl0 = *(const bf16x8*)(kr_l);
    bf16x8 kl1 = *(const bf16x8*)(kr_l + 32);
    f32x4 a1 = {0,0,0,0}, a2 = {0,0,0,0}, a3 = {0,0,0,0};
    a1 = __builtin_amdgcn_mfma_f32_16x16x32_bf16(qh[0], kh0, a1, 0,0,0);
    a2 = __builtin_amdgcn_mfma_f32_16x16x32_bf16(qh[0], kl0, a2, 0,0,0);
    a3 = __builtin_amdgcn_mfma_f32_16x16x32_bf16(ql[0], kh0, a3, 0,0,0);
    a1 = __builtin_amdgcn_mfma_f32_16x16x32_bf16(qh[1], kh1, a1, 0,0,0);
    a2 = __builtin_amdgcn_mfma_f32_16x16x32_bf16(qh[1], kl1, a2, 0,0,0);
    a3 = __builtin_amdgcn_mfma_f32_16x16x32_bf16(ql[1], kh1, a3, 0,0,0);
    #pragma unroll
    for (int r=0;r<4;++r){
      float s = a1[r] + a2[r] + a3[r];
      float p = __expf(s);
      rs[r] += p;
      int row = lg*4 + r;
      *(unsigned short*)(Pb + PB(row, kv0 + lr)) = f2bf(p);
    }
  }

  // ---- phase 2: rowsum reduce (16 kv-lanes, then 8 waves), rinv ----
  #pragma unroll
  for (int m=1; m<16; m<<=1){
    #pragma unroll
    for (int r=0;r<4;++r) rs[r] += __shfl_xor(rs[r], m, 64);
  }
  if (lr == 0){
    #pragma unroll
    for (int r=0;r<4;++r) red[w*QBLK + lg*4 + r] = rs[r];
  }
  __syncthreads();
  if (tid < QBLK){
    float s = 1e-8f;
    #pragma unroll
    for (int ww=0; ww<8; ++ww) s += red[ww*QBLK + tid];
    rinv_s[tid] = 1.0f / s;
  }
  __syncthreads();

  // ---- phase 3: PV via MFMA (A=P from LDS, B=Vt direct global) ----
  {
    int n = w & 3, kvh = w >> 2;
    const unsigned short* Vb = Vt + (size_t)bh*DIM*SEQ
                             + (size_t)(n*16 + lr)*SEQ + kvh*1024 + lg*8;
    f32x4 ctx = {0,0,0,0};
    for (int kk=0; kk<32; ++kk){
      bf16x8 pa = *(const bf16x8*)(Pb + PB(lr, kvh*1024 + kk*32 + lg*8));
      bf16x8 vb = *(const bf16x8*)(Vb + kk*32);
      ctx = __builtin_amdgcn_mfma_f32_16x16x32_bf16(pa, vb, ctx, 0,0,0);
    }
    if (kvh == 1){
      #pragma unroll
      for (int r=0;r<4;++r) ctile[(n*QBLK + lg*4 + r)*16 + lr] = ctx[r];
    }
    __syncthreads();
    if (kvh == 0){
      #pragma unroll
      for (int r=0;r<4;++r){
        int row = lg*4 + r;
        float v = (ctx[r] + ctile[(n*QBLK + row)*16 + lr]) * rinv_s[row];
        ctx_out[((size_t)(bh*SEQ) + q0 + row)*DIM + n*16 + lr] = v;
      }
    }
  }

  // ---- phase 4: normalized attn write (read P_lds, scale, coalesced f4) ----
  {
    int q = tid >> 5, c = tid & 31;
    float riq = rinv_s[q];
    float* orow = attn_out + ((size_t)(bh*SEQ) + q0 + q)*SEQ;
    #pragma unroll
    for (int i=0; i<16; ++i){
      int col = i*128 + c*4;
      uint2 pv = *(const uint2*)(Pb + PB(q, col));
      float4 o;
      o.x = bf2f(pv.x & 0xffffu)*riq;
      o.y = bf2f(pv.x >> 16)*riq;
      o.z = bf2f(pv.y & 0xffffu)*riq;
      o.w = bf2f(pv.y >> 16)*riq;
      *(float4*)(orow + col) = o;
    }
  }
}

extern "C" void kernel_launch(void* const* d_in, const int* in_sizes, int n_in,
                              void* d_out, int out_size, void* d_ws, size_t ws_size,
                              hipStream_t stream) {
  const float* Q = (const float*)d_in[0];
  const float* K = (const float*)d_in[1];
  const float* V = (const float*)d_in[2];
  float* ctx_out  = (float*)d_out;
  float* attn_out = ctx_out + (size_t)NELEM;

  unsigned short* Khi = (unsigned short*)d_ws;
  unsigned short* Klo = Khi + (size_t)NELEM;
  unsigned short* Vt  = Klo + (size_t)NELEM;

  prep_split_k<<<1024, 256, 0, stream>>>(K, Khi, Klo);
  prep_transpose_v<<<BH*32, 256, 0, stream>>>(V, Vt);
  attn_main<<<NBLK, 512, 0, stream>>>(Q, Khi, Klo, Vt, ctx_out, attn_out);
}